// Round 7
// baseline (824.859 us; speedup 1.0000x reference)
//
#include <hip/hip_runtime.h>
#include <math.h>

// ---------------- workspace layout ----------------
static const size_t OFF_TW = 0;
static const size_t OFF_V  = 32768;
static const size_t OFF_AT = OFF_V  + (size_t)16 * 64 * 4104 * 8;
static const size_t OFF_ZX = OFF_AT + (size_t)16 * 32 * 8192 * 8;
static const size_t WS_NEED = OFF_ZX + (size_t)128 * 32 * 4096 * 8;

// ---------------- twiddle init ----------------
__global__ void __launch_bounds__(256) k_init_tw(float2* __restrict__ tw)
{
    int k = blockIdx.x * 256 + threadIdx.x;
    if (k < 4096) {
        double a = (double)k * (3.14159265358979323846 / 4096.0);
        tw[k] = make_float2((float)cos(a), (float)(-sin(a)));
    }
}

// ---------------- dpb MLP ----------------
// Accumulators stay in registers (static j indexing); the k-loop stays ROLLED
// and reads b[k] from a private LDS row. Full unroll of both loops (round 0
// fix) made ~96 KB of code > 32 KB I$ -> fetch-stall bound (~230 us).
// LDS row stride 65 dwords: bank = (tid*65+k)%32 = (tid+k)%32 -> 2 lanes/bank
// for a 64-lane wave == free.
__device__ __forceinline__ void ln_relu_arr(float* b,
                                            const float* __restrict__ g,
                                            const float* __restrict__ be)
{
    float s0 = 0, s1 = 0, s2 = 0, s3 = 0;
    #pragma unroll
    for (int k = 0; k < 64; k += 4) {
        s0 += b[k]; s1 += b[k + 1]; s2 += b[k + 2]; s3 += b[k + 3];
    }
    float m = (s0 + s1 + s2 + s3) * (1.0f / 64.0f);
    float v0 = 0, v1 = 0, v2 = 0, v3 = 0;
    #pragma unroll
    for (int k = 0; k < 64; k += 4) {
        float c0 = b[k] - m, c1 = b[k + 1] - m, c2 = b[k + 2] - m, c3 = b[k + 3] - m;
        v0 = fmaf(c0, c0, v0); v1 = fmaf(c1, c1, v1);
        v2 = fmaf(c2, c2, v2); v3 = fmaf(c3, c3, v3);
    }
    float inv = rsqrtf((v0 + v1 + v2 + v3) * (1.0f / 64.0f) + 1e-5f);
    #pragma unroll
    for (int k = 0; k < 64; ++k)
        b[k] = fmaxf(fmaf((b[k] - m) * inv, g[k], be[k]), 0.0f);
}

__device__ __forceinline__ void store_row(float* __restrict__ row, const float* a)
{
    #pragma unroll
    for (int k = 0; k < 64; ++k) row[k] = a[k];
}

template<int JN>
__device__ __forceinline__ void matmul_lds(const float* __restrict__ row, float* o,
                                           const float* __restrict__ w,
                                           const float* __restrict__ bias)
{
    #pragma unroll
    for (int j = 0; j < JN; ++j) o[j] = bias[j];
    #pragma unroll 4
    for (int k = 0; k < 64; ++k) {
        float bk = row[k];                 // ds_read_b32, conflict-free
        const float* wr = w + k * JN;      // uniform -> scalar loads
        #pragma unroll
        for (int j = 0; j < JN; ++j) o[j] = fmaf(bk, wr[j], o[j]);
    }
}

__global__ void __launch_bounds__(128) k_dpb(
    const float* __restrict__ w0,  const float* __restrict__ b0,
    const float* __restrict__ g1,  const float* __restrict__ be1,
    const float* __restrict__ w1,  const float* __restrict__ b1,
    const float* __restrict__ g2,  const float* __restrict__ be2,
    const float* __restrict__ w2,  const float* __restrict__ b2,
    const float* __restrict__ g3,  const float* __restrict__ be3,
    const float* __restrict__ w3,  const float* __restrict__ b3,
    float* __restrict__ aTf)
{
    __shared__ float rowbuf[128 * 65];
    float* row = &rowbuf[threadIdx.x * 65];

    int e  = blockIdx.x * 128 + threadIdx.x;
    int r  = e & 8191;
    int dd = e >> 13;
    const float scale = (float)(1.0 / 262080.0);
    float u;
    if (r == 0 || r == 4096) u = 0.0f;
    else if (r < 4096)       u = (float)((r - 1) * 64 + dd + 1) * scale;
    else                     u = -(float)(262080 - ((r - 4097) * 64 + dd)) * scale;

    float a[64], o[64];
    #pragma unroll
    for (int j = 0; j < 64; ++j) a[j] = fmaf(u, w0[j], b0[j]);
    ln_relu_arr(a, g1, be1);
    store_row(row, a);
    matmul_lds<64>(row, o, w1, b1);
    ln_relu_arr(o, g2, be2);
    store_row(row, o);
    matmul_lds<64>(row, a, w2, b2);
    ln_relu_arr(a, g3, be3);
    store_row(row, a);
    float f[16];
    matmul_lds<16>(row, f, w3, b3);

    #pragma unroll
    for (int h = 0; h < 16; ++h) {
        size_t idx = ((size_t)((h << 5) + (dd >> 1)) * 8192 + r) * 2 + (dd & 1);
        aTf[idx] = f[h];
    }
}

// ---------------- LDS swizzle for float2[4096] ----------------
// sw(p) = p ^ ((p>>4)&15) ^ ((p>>8)&1): involution (XORs only bits 0-3,
// driven by bits 4-8). Keeps every FFT access pattern (contiguous fill,
// rev12 gather, stride-8 writeback, r8 strides 8/64/512, j<->4096-j pairing)
// at the minimal 4 dwords/bank per wave64 ds_*_b64.
__device__ __forceinline__ int sw(int a)
{
    return a ^ ((a >> 4) & 15) ^ ((a >> 8) & 1);
}

__device__ __forceinline__ float2 cmul(float2 a, float2 b)
{
    return make_float2(fmaf(a.x, b.x, -(a.y * b.y)), fmaf(a.x, b.y, a.y * b.x));
}

// multiply by forward twiddle (wr, wi); INV conjugates the twiddle
template<bool INV>
__device__ __forceinline__ float2 twm(float2 a, float wr, float wi)
{
    float i = INV ? -wi : wi;
    return make_float2(fmaf(a.x, wr, -(a.y * i)), fmaf(a.x, i, a.y * wr));
}

// ---------------- in-register 8-point DIT FFT ----------------
template<bool INV>
__device__ __forceinline__ void fft8(float2* z)
{
    const float SQ = 0.70710678118654752440f;
    #pragma unroll
    for (int b = 0; b < 8; b += 2) {
        float2 u = z[b], t = z[b + 1];
        z[b]     = make_float2(u.x + t.x, u.y + t.y);
        z[b + 1] = make_float2(u.x - t.x, u.y - t.y);
    }
    const float w4r[2] = {1.0f, 0.0f};
    const float w4i[2] = {0.0f, -1.0f};
    #pragma unroll
    for (int b = 0; b < 8; b += 4) {
        #pragma unroll
        for (int j = 0; j < 2; ++j) {
            float2 u = z[b + j];
            float2 t = twm<INV>(z[b + j + 2], w4r[j], w4i[j]);
            z[b + j]     = make_float2(u.x + t.x, u.y + t.y);
            z[b + j + 2] = make_float2(u.x - t.x, u.y - t.y);
        }
    }
    const float w8r[4] = {1.0f, SQ, 0.0f, -SQ};
    const float w8i[4] = {0.0f, -SQ, -1.0f, -SQ};
    #pragma unroll
    for (int j = 0; j < 4; ++j) {
        float2 u = z[j];
        float2 t = twm<INV>(z[j + 4], w8r[j], w8i[j]);
        z[j]     = make_float2(u.x + t.x, u.y + t.y);
        z[j + 4] = make_float2(u.x - t.x, u.y - t.y);
    }
}

// ---------------- radix-8 LDS butterfly ----------------
// Fuses 3 radix-2 DIT stages (spans L,2L,4L). tw scale s: 8*L*s == 8192
// (same table works for the 4096-pt FFT since W_4096^k = tw[2k]).
template<bool INV>
__device__ __forceinline__ void r8(float2* __restrict__ Z, int base, int j, int L, int s,
                                   const float2* __restrict__ tw)
{
    int addr[8];
    #pragma unroll
    for (int m = 0; m < 8; ++m) addr[m] = sw(base + j + L * m);
    float2 t1 = tw[j * s], t2 = tw[2 * j * s], t4 = tw[4 * j * s];
    if (INV) { t1.y = -t1.y; t2.y = -t2.y; t4.y = -t4.y; }
    float2 T3 = cmul(t1, t2), T5 = cmul(t1, t4), T6 = cmul(t2, t4), T7 = cmul(T3, t4);
    float2 z[8];
    z[0] = Z[addr[0]];
    z[1] = cmul(Z[addr[1]], t4);
    z[2] = cmul(Z[addr[2]], t2);
    z[3] = cmul(Z[addr[3]], T6);
    z[4] = cmul(Z[addr[4]], t1);
    z[5] = cmul(Z[addr[5]], T5);
    z[6] = cmul(Z[addr[6]], T3);
    z[7] = cmul(Z[addr[7]], T7);
    fft8<INV>(z);
    #pragma unroll
    for (int q = 0; q < 8; ++q) Z[addr[q]] = z[q];
}

// ---------------- first 3 stages in registers (8 pts/thread) ----------------
template<int L, bool INV>
__device__ __forceinline__ void reg_stage8(float* xr, float* xi,
                                           const float2* __restrict__ tw)
{
    #pragma unroll
    for (int b = 0; b < 8; b += 2 * L) {
        #pragma unroll
        for (int j = 0; j < L; ++j) {
            float2 w = tw[j * (4096 / L)];
            float wr = w.x, wi = INV ? -w.y : w.y;
            int i0 = b + j, i1 = b + j + L;
            float tr = xr[i1] * wr - xi[i1] * wi;
            float ti = xr[i1] * wi + xi[i1] * wr;
            xr[i1] = xr[i0] - tr; xi[i1] = xi[i0] - ti;
            xr[i0] += tr;         xi[i0] += ti;
        }
    }
}

// ---------------- 4096-pt complex FFT: natural in/out, 512 threads ----------
// 12 stages = reg fft8 (spans 1..4) + r8 (8..32) + r8 (64..256) + r8 (512..2048).
// 32 KiB LDS -> 3 independent blocks/CU stagger their LDS/VALU/barrier phases.
// Caller must __syncthreads() after populating Z and before calling.
template<bool INV>
__device__ __forceinline__ void fft4096_lds(float2* __restrict__ Z,
                                            const float2* __restrict__ tw)
{
    const int t  = threadIdx.x;                       // 512 threads
    const int r9 = (int)(__brev((unsigned)t) >> 23);  // rev9(t)
    float xr[8], xi[8];
    #pragma unroll
    for (int i = 0; i < 8; ++i) {
        int r3 = (int)(__brev((unsigned)i) >> 29);    // rev3(i)
        float2 v = Z[sw((r3 << 9) | r9)];             // rev12(8t+i)
        xr[i] = v.x; xi[i] = v.y;
    }
    __syncthreads();
    reg_stage8<1, INV>(xr, xi, tw);
    reg_stage8<2, INV>(xr, xi, tw);
    reg_stage8<4, INV>(xr, xi, tw);
    #pragma unroll
    for (int i = 0; i < 8; ++i) Z[sw(8 * t + i)] = make_float2(xr[i], xi[i]);
    __syncthreads();
    // spans 8..32: 64 groups of 64
    r8<INV>(Z, (t >> 3) * 64, t & 7, 8, 128, tw);
    __syncthreads();
    // spans 64..256: 8 groups of 512
    r8<INV>(Z, (t >> 6) * 512, t & 63, 64, 16, tw);
    __syncthreads();
    // spans 512..2048: single group of 4096
    r8<INV>(Z, 0, t, 512, 2, tw);
    __syncthreads();
}

// ---------------- V = rfft(a) / 8192 via even/odd split ----------------
// FFT8192(a)[2j]   = FFT4096(a[n] + a[n+4096])[j]
// FFT8192(a)[2j+1] = FFT4096((a[n] - a[n+4096]) * tw[n])[j]
// Conjugate mirror 8192-k stays within the same parity class.
__global__ void __launch_bounds__(512, 3) k_vfft(const float2* __restrict__ aT,
                                                 const float2* __restrict__ tw,
                                                 float2* __restrict__ V)
{
    __shared__ float2 Z[4096];
    int blk = blockIdx.x;          // (h*32+p)*2 + eo
    int pair = blk >> 1, eo = blk & 1;
    int h = pair >> 5, p = pair & 31;
    const float2* ac = aT + (size_t)pair * 8192;
    int t = threadIdx.x;
    if (eo == 0) {
        #pragma unroll
        for (int i = 0; i < 8; ++i) {
            int idx = i * 512 + t;
            float2 a = ac[idx], b = ac[idx + 4096];
            Z[sw(idx)] = make_float2(a.x + b.x, a.y + b.y);
        }
    } else {
        #pragma unroll
        for (int i = 0; i < 8; ++i) {
            int idx = i * 512 + t;
            float2 a = ac[idx], b = ac[idx + 4096];
            Z[sw(idx)] = cmul(make_float2(a.x - b.x, a.y - b.y), tw[idx]);
        }
    }
    __syncthreads();
    fft4096_lds<false>(Z, tw);
    const float s = 1.0f / 8192.0f;
    float2* V0 = V + (size_t)(h * 64 + 2 * p) * 4104;
    float2* V1 = V0 + 4104;
    if (eo == 0) {
        for (int j = t; j <= 2048; j += 512) {
            int jm = (4096 - j) & 4095;
            float2 z1 = Z[sw(j)], z2 = Z[sw(jm)];
            float zr1 = z1.x, zi1 = z1.y;
            float zr2 = z2.x, zi2 = -z2.y;
            V0[2 * j] = make_float2(0.5f * (zr1 + zr2) * s, 0.5f * (zi1 + zi2) * s);
            V1[2 * j] = make_float2(0.5f * (zi1 - zi2) * s, -0.5f * (zr1 - zr2) * s);
        }
    } else {
        for (int j = t; j < 2048; j += 512) {
            int jm = 4095 - j;
            float2 z1 = Z[sw(j)], z2 = Z[sw(jm)];
            float zr1 = z1.x, zi1 = z1.y;
            float zr2 = z2.x, zi2 = -z2.y;
            V0[2 * j + 1] = make_float2(0.5f * (zr1 + zr2) * s, 0.5f * (zi1 + zi2) * s);
            V1[2 * j + 1] = make_float2(0.5f * (zi1 - zi2) * s, -0.5f * (zr1 - zr2) * s);
        }
    }
}

// ---------------- pack x: (b,h,r,d) -> float2[bh][p][r] ----------------
__global__ void __launch_bounds__(256) k_pack_x(const float* __restrict__ x,
                                                float2* __restrict__ zx)
{
    int blk = blockIdx.x;
    int bh = blk >> 7, rt = blk & 127, r0 = rt << 5;
    __shared__ float tile[64][33];
    const float* xp = x + (size_t)bh * 4096 * 64;
    int tid = threadIdx.x;
    #pragma unroll
    for (int i = 0; i < 8; ++i) {
        int idx = i * 256 + tid;
        int rr = idx >> 6, d = idx & 63;
        tile[d][rr] = xp[(size_t)(r0 + rr) * 64 + d];
    }
    __syncthreads();
    float2* zp = zx + (size_t)bh * 32 * 4096;
    #pragma unroll
    for (int i = 0; i < 4; ++i) {
        int idx = i * 256 + tid;
        int p = idx >> 5, rr = idx & 31;
        zp[(size_t)p * 4096 + r0 + rr] = make_float2(tile[2 * p][rr], tile[2 * p + 1][rr]);
    }
}

// ---------------- conv via even/odd split: two 4096 FFT pipelines ----------
// E pass: Xe = FFT4096(zc) -> multiply V at even bins -> E' = IFFT4096 (stash
// in 16 regs). O pass: Xo = FFT4096(zc*tw) -> odd bins -> O' = IFFT4096.
// y[n] = E'[n] + conj(tw[n]) * O'[n]  (V already carries the 1/8192).
__global__ void __launch_bounds__(512, 3) k_conv(float2* __restrict__ zx,
                                                 const float2* __restrict__ V,
                                                 const float2* __restrict__ tw)
{
    __shared__ float2 Z[4096];
    int blk = blockIdx.x;            // bh*32 + p
    int bh = blk >> 5, p = blk & 31, h = bh & 15;
    float2* zc = zx + (size_t)blk * 4096;
    int t = threadIdx.x;
    const float2* V0 = V + (size_t)(h * 64 + 2 * p) * 4104;
    const float2* V1 = V0 + 4104;

    // ---- even-bin pass ----
    #pragma unroll
    for (int i = 0; i < 8; ++i) {
        int idx = i * 512 + t;
        Z[sw(idx)] = zc[idx];
    }
    __syncthreads();
    fft4096_lds<false>(Z, tw);
    for (int j = t; j <= 2048; j += 512) {
        int jm = (4096 - j) & 4095;
        float2 z1 = Z[sw(j)], z2 = Z[sw(jm)];
        float zr1 = z1.x, zi1 = z1.y;
        float zr2 = z2.x, zi2 = -z2.y;
        float x0r = 0.5f * (zr1 + zr2), x0i = 0.5f * (zi1 + zi2);
        float x1r = 0.5f * (zi1 - zi2), x1i = -0.5f * (zr1 - zr2);
        float2 v0 = V0[2 * j], v1 = V1[2 * j];
        float y0r = v0.x * x0r - v0.y * x0i, y0i = v0.x * x0i + v0.y * x0r;
        float y1r = v1.x * x1r - v1.y * x1i, y1i = v1.x * x1i + v1.y * x1r;
        Z[sw(j)] = make_float2(y0r - y1i, y0i + y1r);
        if (j > 0 && j < 2048)
            Z[sw(jm)] = make_float2(y0r + y1i, y1r - y0i);
    }
    __syncthreads();
    fft4096_lds<true>(Z, tw);
    float er[8], ei[8];
    #pragma unroll
    for (int i = 0; i < 8; ++i) {
        float2 v = Z[sw(i * 512 + t)];
        er[i] = v.x; ei[i] = v.y;
    }
    __syncthreads();                 // protect stash reads from O-fill writes

    // ---- odd-bin pass ----
    #pragma unroll
    for (int i = 0; i < 8; ++i) {
        int idx = i * 512 + t;
        Z[sw(idx)] = cmul(zc[idx], tw[idx]);
    }
    __syncthreads();
    fft4096_lds<false>(Z, tw);
    for (int j = t; j < 2048; j += 512) {
        int jm = 4095 - j;
        float2 z1 = Z[sw(j)], z2 = Z[sw(jm)];
        float zr1 = z1.x, zi1 = z1.y;
        float zr2 = z2.x, zi2 = -z2.y;
        float x0r = 0.5f * (zr1 + zr2), x0i = 0.5f * (zi1 + zi2);
        float x1r = 0.5f * (zi1 - zi2), x1i = -0.5f * (zr1 - zr2);
        float2 v0 = V0[2 * j + 1], v1 = V1[2 * j + 1];
        float y0r = v0.x * x0r - v0.y * x0i, y0i = v0.x * x0i + v0.y * x0r;
        float y1r = v1.x * x1r - v1.y * x1i, y1i = v1.x * x1i + v1.y * x1r;
        Z[sw(j)]  = make_float2(y0r - y1i, y0i + y1r);
        Z[sw(jm)] = make_float2(y0r + y1i, y1r - y0i);
    }
    __syncthreads();
    fft4096_lds<true>(Z, tw);
    // ---- combine + writeback ----
    #pragma unroll
    for (int i = 0; i < 8; ++i) {
        int idx = i * 512 + t;
        float2 o = Z[sw(idx)];
        float2 w = tw[idx];          // conj(tw[n]) = W_8192^{-n}
        float yr = er[i] + (w.x * o.x + w.y * o.y);
        float yi = ei[i] + (w.x * o.y - w.y * o.x);
        zc[idx] = make_float2(yr, yi);
    }
}

// ---------------- unpack: float2[bh][p][r] -> out(b,h,r,d) ----------------
__global__ void __launch_bounds__(256) k_unpack_out(const float2* __restrict__ zo,
                                                    float* __restrict__ out)
{
    int blk = blockIdx.x;
    int bh = blk >> 7, rt = blk & 127, r0 = rt << 5;
    __shared__ float tile[64][33];
    const float2* zp = zo + (size_t)bh * 32 * 4096;
    int tid = threadIdx.x;
    #pragma unroll
    for (int i = 0; i < 4; ++i) {
        int idx = i * 256 + tid;
        int p = idx >> 5, rr = idx & 31;
        float2 v = zp[(size_t)p * 4096 + r0 + rr];
        tile[2 * p][rr] = v.x; tile[2 * p + 1][rr] = v.y;
    }
    __syncthreads();
    float* op = out + (size_t)bh * 4096 * 64;
    #pragma unroll
    for (int i = 0; i < 8; ++i) {
        int idx = i * 256 + tid;
        int rr = idx >> 6, d = idx & 63;
        op[(size_t)(r0 + rr) * 64 + d] = tile[d][rr];
    }
}

extern "C" void kernel_launch(void* const* d_in, const int* in_sizes, int n_in,
                              void* d_out, int out_size, void* d_ws, size_t ws_size,
                              hipStream_t stream)
{
    (void)in_sizes; (void)n_in; (void)out_size;
    const float* x   = (const float*)d_in[0];
    const float* w0  = (const float*)d_in[1];
    const float* b0  = (const float*)d_in[2];
    const float* g1  = (const float*)d_in[3];
    const float* be1 = (const float*)d_in[4];
    const float* w1  = (const float*)d_in[5];
    const float* b1  = (const float*)d_in[6];
    const float* g2  = (const float*)d_in[7];
    const float* be2 = (const float*)d_in[8];
    const float* w2  = (const float*)d_in[9];
    const float* b2  = (const float*)d_in[10];
    const float* g3  = (const float*)d_in[11];
    const float* be3 = (const float*)d_in[12];
    const float* w3  = (const float*)d_in[13];
    const float* b3  = (const float*)d_in[14];
    float* out = (float*)d_out;
    char* ws = (char*)d_ws;
    if (ws_size < WS_NEED) return;

    float2* tw = (float2*)(ws + OFF_TW);
    float2* V  = (float2*)(ws + OFF_V);
    float2* aT = (float2*)(ws + OFF_AT);
    float2* zx = (float2*)(ws + OFF_ZX);

    k_init_tw<<<16, 256, 0, stream>>>(tw);
    k_dpb<<<4096, 128, 0, stream>>>(w0, b0, g1, be1, w1, b1, g2, be2,
                                    w2, b2, g3, be3, w3, b3, (float*)aT);
    k_vfft<<<1024, 512, 0, stream>>>(aT, tw, V);
    k_pack_x<<<16384, 256, 0, stream>>>(x, zx);
    k_conv<<<4096, 512, 0, stream>>>(zx, V, tw);
    k_unpack_out<<<16384, 256, 0, stream>>>((const float2*)zx, out);
}

// Round 8
// 719.159 us; speedup vs baseline: 1.1470x; 1.1470x over previous
//
#include <hip/hip_runtime.h>
#include <math.h>

// ---------------- workspace layout ----------------
static const size_t OFF_TW = 0;
static const size_t OFF_V  = 32768;
static const size_t OFF_AT = OFF_V  + (size_t)16 * 64 * 4104 * 8;
static const size_t OFF_ZX = OFF_AT + (size_t)16 * 32 * 8192 * 8;
static const size_t WS_NEED = OFF_ZX + (size_t)128 * 32 * 4096 * 8;

// ---------------- twiddle init ----------------
__global__ void __launch_bounds__(256) k_init_tw(float2* __restrict__ tw)
{
    int k = blockIdx.x * 256 + threadIdx.x;
    if (k < 4096) {
        double a = (double)k * (3.14159265358979323846 / 4096.0);
        tw[k] = make_float2((float)cos(a), (float)(-sin(a)));
    }
}

// ---------------- dpb MLP ----------------
// Occupancy model (empirical, rounds 0-7): usable VGPR budget ~256/SIMD;
// waves/EU = floor(256/VGPR), block-granular. 512-thr blocks co-reside (x2)
// only at VGPR<=64.
__device__ __forceinline__ void ln_relu_arr(float* b,
                                            const float* __restrict__ g,
                                            const float* __restrict__ be)
{
    float s0 = 0, s1 = 0, s2 = 0, s3 = 0;
    #pragma unroll
    for (int k = 0; k < 64; k += 4) {
        s0 += b[k]; s1 += b[k + 1]; s2 += b[k + 2]; s3 += b[k + 3];
    }
    float m = (s0 + s1 + s2 + s3) * (1.0f / 64.0f);
    float v0 = 0, v1 = 0, v2 = 0, v3 = 0;
    #pragma unroll
    for (int k = 0; k < 64; k += 4) {
        float c0 = b[k] - m, c1 = b[k + 1] - m, c2 = b[k + 2] - m, c3 = b[k + 3] - m;
        v0 = fmaf(c0, c0, v0); v1 = fmaf(c1, c1, v1);
        v2 = fmaf(c2, c2, v2); v3 = fmaf(c3, c3, v3);
    }
    float inv = rsqrtf((v0 + v1 + v2 + v3) * (1.0f / 64.0f) + 1e-5f);
    #pragma unroll
    for (int k = 0; k < 64; ++k)
        b[k] = fmaxf(fmaf((b[k] - m) * inv, g[k], be[k]), 0.0f);
}

__device__ __forceinline__ void store_row(float* __restrict__ row, const float* a)
{
    #pragma unroll
    for (int k = 0; k < 64; ++k) row[k] = a[k];
}

template<int JN>
__device__ __forceinline__ void matmul_lds(const float* __restrict__ row, float* o,
                                           const float* __restrict__ w,
                                           const float* __restrict__ bias)
{
    #pragma unroll
    for (int j = 0; j < JN; ++j) o[j] = bias[j];
    #pragma unroll 4
    for (int k = 0; k < 64; ++k) {
        float bk = row[k];                 // ds_read_b32, conflict-free
        const float* wr = w + k * JN;      // uniform
        #pragma unroll
        for (int j = 0; j < JN; ++j) o[j] = fmaf(bk, wr[j], o[j]);
    }
}

// Block = one dd-pair (2q, 2q+1) x 64 consecutive r: tid<64 -> dd=2q,
// tid>=64 -> dd=2q+1. Epilogue transposes f[16] through (reused) LDS and
// writes COALESCED float2 (512 B contiguous per h) instead of the previous
// 4 B-granule stride-8 scatter (which half-filled lines shared across blocks).
__global__ void __launch_bounds__(128) k_dpb(
    const float* __restrict__ w0,  const float* __restrict__ b0,
    const float* __restrict__ g1,  const float* __restrict__ be1,
    const float* __restrict__ w1,  const float* __restrict__ b1,
    const float* __restrict__ g2,  const float* __restrict__ be2,
    const float* __restrict__ w2,  const float* __restrict__ b2,
    const float* __restrict__ g3,  const float* __restrict__ be3,
    const float* __restrict__ w3,  const float* __restrict__ b3,
    float2* __restrict__ aT2)
{
    __shared__ float smem[128 * 65];       // per-thread row; reused as obuf
    int tid = threadIdx.x;
    float* row = &smem[tid * 65];          // stride 65: bank (tid+k)&31, free

    int q  = blockIdx.x >> 7;              // dd-pair index 0..31
    int rt = blockIdx.x & 127;             // r-tile 0..127
    int rr = tid & 63, par = tid >> 6;
    int r  = rt * 64 + rr;
    int dd = 2 * q + par;
    const float scale = (float)(1.0 / 262080.0);
    float u;
    if (r == 0 || r == 4096) u = 0.0f;
    else if (r < 4096)       u = (float)((r - 1) * 64 + dd + 1) * scale;
    else                     u = -(float)(262080 - ((r - 4097) * 64 + dd)) * scale;

    float a[64], o[64];
    #pragma unroll
    for (int j = 0; j < 64; ++j) a[j] = fmaf(u, w0[j], b0[j]);
    ln_relu_arr(a, g1, be1);
    store_row(row, a);
    matmul_lds<64>(row, o, w1, b1);
    ln_relu_arr(o, g2, be2);
    store_row(row, o);
    matmul_lds<64>(row, a, w2, b2);
    ln_relu_arr(a, g3, be3);
    store_row(row, a);
    float f[16];
    matmul_lds<16>(row, f, w3, b3);

    __syncthreads();                       // all row reads done before reuse
    #pragma unroll
    for (int h = 0; h < 16; ++h)
        smem[(h * 64 + rr) * 2 + par] = f[h];
    __syncthreads();
    const float2* ob = (const float2*)smem;    // [16][64]
    #pragma unroll
    for (int i = 0; i < 8; ++i) {
        int ii = i * 128 + tid;            // 0..1023 over (h, r2)
        int h = ii >> 6, r2 = ii & 63;
        aT2[((size_t)(h * 32 + q)) * 8192 + (size_t)rt * 64 + r2] = ob[ii];
    }
}

// ---------------- LDS swizzle for float2[4096] ----------------
__device__ __forceinline__ int sw(int a)
{
    return a ^ ((a >> 4) & 15) ^ ((a >> 8) & 1);
}

__device__ __forceinline__ float2 cmul(float2 a, float2 b)
{
    return make_float2(fmaf(a.x, b.x, -(a.y * b.y)), fmaf(a.x, b.y, a.y * b.x));
}

template<bool INV>
__device__ __forceinline__ float2 twm(float2 a, float wr, float wi)
{
    float i = INV ? -wi : wi;
    return make_float2(fmaf(a.x, wr, -(a.y * i)), fmaf(a.x, i, a.y * wr));
}

// ---------------- in-register 8-point DIT FFT ----------------
template<bool INV>
__device__ __forceinline__ void fft8(float2* z)
{
    const float SQ = 0.70710678118654752440f;
    #pragma unroll
    for (int b = 0; b < 8; b += 2) {
        float2 u = z[b], t = z[b + 1];
        z[b]     = make_float2(u.x + t.x, u.y + t.y);
        z[b + 1] = make_float2(u.x - t.x, u.y - t.y);
    }
    const float w4r[2] = {1.0f, 0.0f};
    const float w4i[2] = {0.0f, -1.0f};
    #pragma unroll
    for (int b = 0; b < 8; b += 4) {
        #pragma unroll
        for (int j = 0; j < 2; ++j) {
            float2 u = z[b + j];
            float2 t = twm<INV>(z[b + j + 2], w4r[j], w4i[j]);
            z[b + j]     = make_float2(u.x + t.x, u.y + t.y);
            z[b + j + 2] = make_float2(u.x - t.x, u.y - t.y);
        }
    }
    const float w8r[4] = {1.0f, SQ, 0.0f, -SQ};
    const float w8i[4] = {0.0f, -SQ, -1.0f, -SQ};
    #pragma unroll
    for (int j = 0; j < 4; ++j) {
        float2 u = z[j];
        float2 t = twm<INV>(z[j + 4], w8r[j], w8i[j]);
        z[j]     = make_float2(u.x + t.x, u.y + t.y);
        z[j + 4] = make_float2(u.x - t.x, u.y - t.y);
    }
}

// ---------------- radix-8 LDS butterfly ----------------
template<bool INV>
__device__ __forceinline__ void r8(float2* __restrict__ Z, int base, int j, int L, int s,
                                   const float2* __restrict__ tw)
{
    int addr[8];
    #pragma unroll
    for (int m = 0; m < 8; ++m) addr[m] = sw(base + j + L * m);
    float2 t1 = tw[j * s], t2 = tw[2 * j * s], t4 = tw[4 * j * s];
    if (INV) { t1.y = -t1.y; t2.y = -t2.y; t4.y = -t4.y; }
    float2 T3 = cmul(t1, t2), T5 = cmul(t1, t4), T6 = cmul(t2, t4), T7 = cmul(T3, t4);
    float2 z[8];
    z[0] = Z[addr[0]];
    z[1] = cmul(Z[addr[1]], t4);
    z[2] = cmul(Z[addr[2]], t2);
    z[3] = cmul(Z[addr[3]], T6);
    z[4] = cmul(Z[addr[4]], t1);
    z[5] = cmul(Z[addr[5]], T5);
    z[6] = cmul(Z[addr[6]], T3);
    z[7] = cmul(Z[addr[7]], T7);
    fft8<INV>(z);
    #pragma unroll
    for (int q = 0; q < 8; ++q) Z[addr[q]] = z[q];
}

// ---------------- first 3 stages in registers (8 pts/thread) ----------------
template<int L, bool INV>
__device__ __forceinline__ void reg_stage8(float* xr, float* xi,
                                           const float2* __restrict__ tw)
{
    #pragma unroll
    for (int b = 0; b < 8; b += 2 * L) {
        #pragma unroll
        for (int j = 0; j < L; ++j) {
            float2 w = tw[j * (4096 / L)];
            float wr = w.x, wi = INV ? -w.y : w.y;
            int i0 = b + j, i1 = b + j + L;
            float tr = xr[i1] * wr - xi[i1] * wi;
            float ti = xr[i1] * wi + xi[i1] * wr;
            xr[i1] = xr[i0] - tr; xi[i1] = xi[i0] - ti;
            xr[i0] += tr;         xi[i0] += ti;
        }
    }
}

// ---------------- 4096-pt complex FFT: natural in/out, 512 threads ----------
template<bool INV>
__device__ __forceinline__ void fft4096_lds(float2* __restrict__ Z,
                                            const float2* __restrict__ tw)
{
    const int t  = threadIdx.x;                       // 512 threads
    const int r9 = (int)(__brev((unsigned)t) >> 23);  // rev9(t)
    float xr[8], xi[8];
    #pragma unroll
    for (int i = 0; i < 8; ++i) {
        int r3 = (int)(__brev((unsigned)i) >> 29);    // rev3(i)
        float2 v = Z[sw((r3 << 9) | r9)];             // rev12(8t+i)
        xr[i] = v.x; xi[i] = v.y;
    }
    __syncthreads();
    reg_stage8<1, INV>(xr, xi, tw);
    reg_stage8<2, INV>(xr, xi, tw);
    reg_stage8<4, INV>(xr, xi, tw);
    #pragma unroll
    for (int i = 0; i < 8; ++i) Z[sw(8 * t + i)] = make_float2(xr[i], xi[i]);
    __syncthreads();
    r8<INV>(Z, (t >> 3) * 64, t & 7, 8, 128, tw);
    __syncthreads();
    r8<INV>(Z, (t >> 6) * 512, t & 63, 64, 16, tw);
    __syncthreads();
    r8<INV>(Z, 0, t, 512, 2, tw);
    __syncthreads();
}

// ---------------- V = rfft(a) / 8192 via even/odd split ----------------
// (512,4): empirically caps VGPR at 64 -> two 512-thr blocks co-reside
// (4 waves/EU x 64 = 256 budget), independent barrier groups.
__global__ void __launch_bounds__(512, 4) k_vfft(const float2* __restrict__ aT,
                                                 const float2* __restrict__ tw,
                                                 float2* __restrict__ V)
{
    __shared__ float2 Z[4096];
    int blk = blockIdx.x;          // (h*32+p)*2 + eo
    int pair = blk >> 1, eo = blk & 1;
    int h = pair >> 5, p = pair & 31;
    const float2* ac = aT + (size_t)pair * 8192;
    int t = threadIdx.x;
    if (eo == 0) {
        #pragma unroll
        for (int i = 0; i < 8; ++i) {
            int idx = i * 512 + t;
            float2 a = ac[idx], b = ac[idx + 4096];
            Z[sw(idx)] = make_float2(a.x + b.x, a.y + b.y);
        }
    } else {
        #pragma unroll
        for (int i = 0; i < 8; ++i) {
            int idx = i * 512 + t;
            float2 a = ac[idx], b = ac[idx + 4096];
            Z[sw(idx)] = cmul(make_float2(a.x - b.x, a.y - b.y), tw[idx]);
        }
    }
    __syncthreads();
    fft4096_lds<false>(Z, tw);
    const float s = 1.0f / 8192.0f;
    float2* V0 = V + (size_t)(h * 64 + 2 * p) * 4104;
    float2* V1 = V0 + 4104;
    if (eo == 0) {
        for (int j = t; j <= 2048; j += 512) {
            int jm = (4096 - j) & 4095;
            float2 z1 = Z[sw(j)], z2 = Z[sw(jm)];
            float zr1 = z1.x, zi1 = z1.y;
            float zr2 = z2.x, zi2 = -z2.y;
            V0[2 * j] = make_float2(0.5f * (zr1 + zr2) * s, 0.5f * (zi1 + zi2) * s);
            V1[2 * j] = make_float2(0.5f * (zi1 - zi2) * s, -0.5f * (zr1 - zr2) * s);
        }
    } else {
        for (int j = t; j < 2048; j += 512) {
            int jm = 4095 - j;
            float2 z1 = Z[sw(j)], z2 = Z[sw(jm)];
            float zr1 = z1.x, zi1 = z1.y;
            float zr2 = z2.x, zi2 = -z2.y;
            V0[2 * j + 1] = make_float2(0.5f * (zr1 + zr2) * s, 0.5f * (zi1 + zi2) * s);
            V1[2 * j + 1] = make_float2(0.5f * (zi1 - zi2) * s, -0.5f * (zr1 - zr2) * s);
        }
    }
}

// ---------------- pack x: (b,h,r,d) -> float2[bh][p][r] ----------------
__global__ void __launch_bounds__(256) k_pack_x(const float* __restrict__ x,
                                                float2* __restrict__ zx)
{
    int blk = blockIdx.x;
    int bh = blk >> 7, rt = blk & 127, r0 = rt << 5;
    __shared__ float tile[64][33];
    const float* xp = x + (size_t)bh * 4096 * 64;
    int tid = threadIdx.x;
    #pragma unroll
    for (int i = 0; i < 8; ++i) {
        int idx = i * 256 + tid;
        int rr = idx >> 6, d = idx & 63;
        tile[d][rr] = xp[(size_t)(r0 + rr) * 64 + d];
    }
    __syncthreads();
    float2* zp = zx + (size_t)bh * 32 * 4096;
    #pragma unroll
    for (int i = 0; i < 4; ++i) {
        int idx = i * 256 + tid;
        int p = idx >> 5, rr = idx & 31;
        zp[(size_t)p * 4096 + r0 + rr] = make_float2(tile[2 * p][rr], tile[2 * p + 1][rr]);
    }
}

// ---------------- conv via even/odd split, E' stashed in LDS ----------------
// E pass: FFT4096(zc) -> even V bins -> IFFT4096 -> stash E' into ST (LDS,
// not registers: the 16-reg stash was what pushed round-7 to VGPR=72 > 64
// and killed 2-block co-residency). O pass in Z. Combine:
// y[n] = E'[n] + conj(tw[n])*O'[n].
__global__ void __launch_bounds__(512, 4) k_conv(float2* __restrict__ zx,
                                                 const float2* __restrict__ V,
                                                 const float2* __restrict__ tw)
{
    __shared__ float2 Z[4096];
    __shared__ float2 ST[4096];
    int blk = blockIdx.x;            // bh*32 + p
    int bh = blk >> 5, p = blk & 31, h = bh & 15;
    float2* zc = zx + (size_t)blk * 4096;
    int t = threadIdx.x;
    const float2* V0 = V + (size_t)(h * 64 + 2 * p) * 4104;
    const float2* V1 = V0 + 4104;

    // ---- even-bin pass ----
    #pragma unroll
    for (int i = 0; i < 8; ++i) {
        int idx = i * 512 + t;
        Z[sw(idx)] = zc[idx];
    }
    __syncthreads();
    fft4096_lds<false>(Z, tw);
    for (int j = t; j <= 2048; j += 512) {
        int jm = (4096 - j) & 4095;
        float2 z1 = Z[sw(j)], z2 = Z[sw(jm)];
        float zr1 = z1.x, zi1 = z1.y;
        float zr2 = z2.x, zi2 = -z2.y;
        float x0r = 0.5f * (zr1 + zr2), x0i = 0.5f * (zi1 + zi2);
        float x1r = 0.5f * (zi1 - zi2), x1i = -0.5f * (zr1 - zr2);
        float2 v0 = V0[2 * j], v1 = V1[2 * j];
        float y0r = v0.x * x0r - v0.y * x0i, y0i = v0.x * x0i + v0.y * x0r;
        float y1r = v1.x * x1r - v1.y * x1i, y1i = v1.x * x1i + v1.y * x1r;
        Z[sw(j)] = make_float2(y0r - y1i, y0i + y1r);
        if (j > 0 && j < 2048)
            Z[sw(jm)] = make_float2(y0r + y1i, y1r - y0i);
    }
    __syncthreads();
    fft4096_lds<true>(Z, tw);
    #pragma unroll
    for (int i = 0; i < 8; ++i) {
        int idx = i * 512 + t;
        ST[idx] = Z[sw(idx)];        // linear write, conflict-free
    }
    __syncthreads();                 // stash reads of Z done before O-fill

    // ---- odd-bin pass ----
    #pragma unroll
    for (int i = 0; i < 8; ++i) {
        int idx = i * 512 + t;
        Z[sw(idx)] = cmul(zc[idx], tw[idx]);
    }
    __syncthreads();
    fft4096_lds<false>(Z, tw);
    for (int j = t; j < 2048; j += 512) {
        int jm = 4095 - j;
        float2 z1 = Z[sw(j)], z2 = Z[sw(jm)];
        float zr1 = z1.x, zi1 = z1.y;
        float zr2 = z2.x, zi2 = -z2.y;
        float x0r = 0.5f * (zr1 + zr2), x0i = 0.5f * (zi1 + zi2);
        float x1r = 0.5f * (zi1 - zi2), x1i = -0.5f * (zr1 - zr2);
        float2 v0 = V0[2 * j + 1], v1 = V1[2 * j + 1];
        float y0r = v0.x * x0r - v0.y * x0i, y0i = v0.x * x0i + v0.y * x0r;
        float y1r = v1.x * x1r - v1.y * x1i, y1i = v1.x * x1i + v1.y * x1r;
        Z[sw(j)]  = make_float2(y0r - y1i, y0i + y1r);
        Z[sw(jm)] = make_float2(y0r + y1i, y1r - y0i);
    }
    __syncthreads();
    fft4096_lds<true>(Z, tw);
    // ---- combine + writeback ----
    #pragma unroll
    for (int i = 0; i < 8; ++i) {
        int idx = i * 512 + t;
        float2 o = Z[sw(idx)];
        float2 e = ST[idx];
        float2 w = tw[idx];          // conj(tw[n]) = W_8192^{-n}
        float yr = e.x + (w.x * o.x + w.y * o.y);
        float yi = e.y + (w.x * o.y - w.y * o.x);
        zc[idx] = make_float2(yr, yi);
    }
}

// ---------------- unpack: float2[bh][p][r] -> out(b,h,r,d) ----------------
__global__ void __launch_bounds__(256) k_unpack_out(const float2* __restrict__ zo,
                                                    float* __restrict__ out)
{
    int blk = blockIdx.x;
    int bh = blk >> 7, rt = blk & 127, r0 = rt << 5;
    __shared__ float tile[64][33];
    const float2* zp = zo + (size_t)bh * 32 * 4096;
    int tid = threadIdx.x;
    #pragma unroll
    for (int i = 0; i < 4; ++i) {
        int idx = i * 256 + tid;
        int p = idx >> 5, rr = idx & 31;
        float2 v = zp[(size_t)p * 4096 + r0 + rr];
        tile[2 * p][rr] = v.x; tile[2 * p + 1][rr] = v.y;
    }
    __syncthreads();
    float* op = out + (size_t)bh * 4096 * 64;
    #pragma unroll
    for (int i = 0; i < 8; ++i) {
        int idx = i * 256 + tid;
        int rr = idx >> 6, d = idx & 63;
        op[(size_t)(r0 + rr) * 64 + d] = tile[d][rr];
    }
}

extern "C" void kernel_launch(void* const* d_in, const int* in_sizes, int n_in,
                              void* d_out, int out_size, void* d_ws, size_t ws_size,
                              hipStream_t stream)
{
    (void)in_sizes; (void)n_in; (void)out_size;
    const float* x   = (const float*)d_in[0];
    const float* w0  = (const float*)d_in[1];
    const float* b0  = (const float*)d_in[2];
    const float* g1  = (const float*)d_in[3];
    const float* be1 = (const float*)d_in[4];
    const float* w1  = (const float*)d_in[5];
    const float* b1  = (const float*)d_in[6];
    const float* g2  = (const float*)d_in[7];
    const float* be2 = (const float*)d_in[8];
    const float* w2  = (const float*)d_in[9];
    const float* b2  = (const float*)d_in[10];
    const float* g3  = (const float*)d_in[11];
    const float* be3 = (const float*)d_in[12];
    const float* w3  = (const float*)d_in[13];
    const float* b3  = (const float*)d_in[14];
    float* out = (float*)d_out;
    char* ws = (char*)d_ws;
    if (ws_size < WS_NEED) return;

    float2* tw = (float2*)(ws + OFF_TW);
    float2* V  = (float2*)(ws + OFF_V);
    float2* aT = (float2*)(ws + OFF_AT);
    float2* zx = (float2*)(ws + OFF_ZX);

    k_init_tw<<<16, 256, 0, stream>>>(tw);
    k_dpb<<<4096, 128, 0, stream>>>(w0, b0, g1, be1, w1, b1, g2, be2,
                                    w2, b2, g3, be3, w3, b3, aT);
    k_vfft<<<1024, 512, 0, stream>>>(aT, tw, V);
    k_pack_x<<<16384, 256, 0, stream>>>(x, zx);
    k_conv<<<4096, 512, 0, stream>>>(zx, V, tw);
    k_unpack_out<<<16384, 256, 0, stream>>>((const float2*)zx, out);
}